// Round 8
// baseline (528.468 us; speedup 1.0000x reference)
//
#include <hip/hip_runtime.h>
#include <math.h>

typedef short bf16x8 __attribute__((ext_vector_type(8)));
typedef float f32x4 __attribute__((ext_vector_type(4)));
typedef unsigned short ushort8 __attribute__((ext_vector_type(8)));
typedef unsigned short ushort4v __attribute__((ext_vector_type(4)));

constexpr int R = 128, Cc = 256, E = 768, H = 12;
constexpr int M = R * Cc;                 // 32768 tokens
constexpr size_t TOK = (size_t)M * E;     // 25165824

// fp32 -> bf16 round-to-nearest-even
__device__ __forceinline__ unsigned short f2b(float f) {
  unsigned int u = __float_as_uint(f);
  u += 0x7fff + ((u >> 16) & 1);
  return (unsigned short)(u >> 16);
}

// async global->LDS, 16B per lane. LDS dest must be wave-uniform base + lane*16.
__device__ __forceinline__ void ldst16(const unsigned short* g, unsigned short* l) {
  __builtin_amdgcn_global_load_lds(
      (const __attribute__((address_space(1))) unsigned int*)g,
      (__attribute__((address_space(3))) unsigned int*)l, 16, 0, 0);
}

// ---------------------------------------------------------------------------
__global__ __launch_bounds__(256) void cvt_bf16(const float* __restrict__ in,
                                                unsigned short* __restrict__ out,
                                                int n8) {
  int i = blockIdx.x * 256 + threadIdx.x;
  if (i >= n8) return;
  const float4* p = (const float4*)in;
  float4 a = p[2 * i], b = p[2 * i + 1];
  ushort8 o;
  o[0] = f2b(a.x); o[1] = f2b(a.y); o[2] = f2b(a.z); o[3] = f2b(a.w);
  o[4] = f2b(b.x); o[5] = f2b(b.y); o[6] = f2b(b.z); o[7] = f2b(b.w);
  ((ushort8*)out)[i] = o;
}

// All four weight matrices in one launch.
__global__ __launch_bounds__(256) void cvt_w4(const float* __restrict__ W0,
                                              const float* __restrict__ W1,
                                              const float* __restrict__ W2,
                                              const float* __restrict__ W3,
                                              unsigned short* __restrict__ out) {
  const int region = blockIdx.x / 288;
  const int i = (blockIdx.x % 288) * 256 + threadIdx.x;
  if (i >= 73728) return;
  const float* src = region == 0 ? W0 : (region == 1 ? W1 : (region == 2 ? W2 : W3));
  const float4* p = (const float4*)src;
  float4 a = p[2 * i], b = p[2 * i + 1];
  ushort8 o;
  o[0] = f2b(a.x); o[1] = f2b(a.y); o[2] = f2b(a.z); o[3] = f2b(a.w);
  o[4] = f2b(b.x); o[5] = f2b(b.y); o[6] = f2b(b.z); o[7] = f2b(b.w);
  ((ushort8*)(out + (size_t)region * 589824))[i] = o;
}

// ===========================================================================
// 256x256-tile GEMM body (512 thr = 8 waves as 2Mx4N, per-wave 128x64 out).
// Rationale (R7 post-mortem): 128^2 tiles stage 1/64 B/FLOP and saturate at
// ~9-14 TB/s L2->LDS delivery (the measured wall, MfmaUtil ~25%). 256^2 halves
// staged bytes/FLOP (1/128) -> ~2x headroom at the same delivery rate.
// Schedule = R5's PROVEN skeleton: BK=32 double-buffer (64KB LDS exactly),
// counted vmcnt(4) (stage t+1 stays in flight across barriers), 2 barriers
// per K-step, stage(t+2) after the read-release barrier, setprio on MFMA.
// Swizzle = R7's zero-conflict scheme for 64B rows: global chunk g stored at
// LDS chunk g^((row>>1)&3), same involution on source address and ds_read.
// ===========================================================================
__device__ __forceinline__ void stage256(const unsigned short* __restrict__ A, int lda,
                                         const unsigned short* __restrict__ B, int ldb,
                                         int k0, unsigned short* As, unsigned short* Bs,
                                         int tid) {
  const int r0 = tid >> 2;                              // 0..127
  const int g = ((tid & 3) ^ ((tid >> 3) & 3)) * 8;     // pre-swizzled k-chunk
#pragma unroll
  for (int o = 0; o < 2; ++o) {
    const int row = o * 128 + r0;                       // (row>>1)&3 == (tid>>3)&3
    ldst16(A + (size_t)row * lda + k0 + g, As + o * 4096 + tid * 8);
    ldst16(B + (size_t)row * ldb + k0 + g, Bs + o * 4096 + tid * 8);
  }
}

__device__ __forceinline__ void gemm256(const unsigned short* __restrict__ A, int lda,
                                        const unsigned short* __restrict__ B, int ldb,
                                        int K, unsigned short* As, unsigned short* Bs,
                                        int tid, int ln, int wm, int wn,
                                        f32x4 (&acc)[8][4]) {
  const int nt = K >> 5;
  stage256(A, lda, B, ldb, 0, As, Bs, tid);
  stage256(A, lda, B, ldb, 32, As + 8192, Bs + 8192, tid);
  const int rc = ((ln >> 4) ^ ((ln >> 1) & 3)) * 8;     // swizzled read chunk
  for (int t = 0; t < nt; ++t) {
    const int cur = t & 1;
    // stage(t) landed (stage t+1's 4 loads stay in flight); barrier -> collective.
    if (t + 1 < nt) {
      asm volatile("s_waitcnt vmcnt(4)" ::: "memory");
    } else {
      asm volatile("s_waitcnt vmcnt(0)" ::: "memory");
    }
    __builtin_amdgcn_sched_barrier(0);
    __builtin_amdgcn_s_barrier();
    const unsigned short* Ab = As + cur * 8192;
    const unsigned short* Bb = Bs + cur * 8192;
    bf16x8 a[8], b[4];
#pragma unroll
    for (int i = 0; i < 8; ++i)
      a[i] = *(const bf16x8*)(Ab + (wm + i * 16 + (ln & 15)) * 32 + rc);
#pragma unroll
    for (int j = 0; j < 4; ++j)
      b[j] = *(const bf16x8*)(Bb + (wn + j * 16 + (ln & 15)) * 32 + rc);
    // all reads retired into regs; barrier -> every wave done with buf[cur].
    asm volatile("s_waitcnt lgkmcnt(0)" ::: "memory");
    __builtin_amdgcn_sched_barrier(0);
    __builtin_amdgcn_s_barrier();
    if (t + 2 < nt)
      stage256(A, lda, B, ldb, (t + 2) * 32, As + cur * 8192, Bs + cur * 8192, tid);
    __builtin_amdgcn_s_setprio(1);
#pragma unroll
    for (int i = 0; i < 8; ++i)
#pragma unroll
      for (int j = 0; j < 4; ++j)
        acc[i][j] = __builtin_amdgcn_mfma_f32_16x16x32_bf16(a[i], b[j], acc[i][j], 0, 0, 0);
    __builtin_amdgcn_s_setprio(0);
  }
}

// ===========================================================================
// 128x128-tile body (R5 verbatim — proven, 0 conflicts) for qk_gemm.
// ===========================================================================
__device__ __forceinline__ void stage64(const unsigned short* __restrict__ A, int lda,
                                        const unsigned short* __restrict__ B, int ldb,
                                        int k0, unsigned short* As, unsigned short* Bs,
                                        int wv, int ln, int srow, int scol) {
#pragma unroll
  for (int t = 0; t < 4; ++t) {
    const int ch = wv * 4 + t;
    const int row = ch * 8 + srow;
    ldst16(A + (size_t)row * lda + k0 + scol, As + ch * 512 + ln * 8);
    ldst16(B + (size_t)row * ldb + k0 + scol, Bs + ch * 512 + ln * 8);
  }
}

__device__ __forceinline__ void gemm128(const unsigned short* __restrict__ A, int lda,
                                        const unsigned short* __restrict__ B, int ldb,
                                        int K, unsigned short* As, unsigned short* Bs,
                                        int wv, int ln, int wm, int wn,
                                        f32x4 (&acc)[4][4]) {
  const int srow = ln >> 3;
  const int scol = ((ln & 7) ^ srow) * 8;
  const int nt = K >> 6;
  stage64(A, lda, B, ldb, 0, As, Bs, wv, ln, srow, scol);
  if (nt > 1)
    stage64(A, lda, B, ldb, 64, As + 8192, Bs + 8192, wv, ln, srow, scol);
  for (int t = 0; t < nt; ++t) {
    const int cur = t & 1;
    if (t + 1 < nt) {
      asm volatile("s_waitcnt vmcnt(8)" ::: "memory");
    } else {
      asm volatile("s_waitcnt vmcnt(0)" ::: "memory");
    }
    __builtin_amdgcn_sched_barrier(0);
    __builtin_amdgcn_s_barrier();
    const unsigned short* Ab = As + cur * 8192;
    const unsigned short* Bb = Bs + cur * 8192;
    bf16x8 a[2][4], b[2][4];
#pragma unroll
    for (int dk = 0; dk < 2; ++dk) {
      const int rc = ((dk * 4 + (ln >> 4)) ^ (ln & 7)) * 8;
#pragma unroll
      for (int i = 0; i < 4; ++i)
        a[dk][i] = *(const bf16x8*)(Ab + (wm + i * 16 + (ln & 15)) * 64 + rc);
#pragma unroll
      for (int j = 0; j < 4; ++j)
        b[dk][j] = *(const bf16x8*)(Bb + (wn + j * 16 + (ln & 15)) * 64 + rc);
    }
    asm volatile("s_waitcnt lgkmcnt(0)" ::: "memory");
    __builtin_amdgcn_sched_barrier(0);
    __builtin_amdgcn_s_barrier();
    if (t + 2 < nt)
      stage64(A, lda, B, ldb, (t + 2) * 64, As + cur * 8192, Bs + cur * 8192,
              wv, ln, srow, scol);
#pragma unroll
    for (int dk = 0; dk < 2; ++dk)
#pragma unroll
      for (int i = 0; i < 4; ++i)
#pragma unroll
        for (int j = 0; j < 4; ++j)
          acc[i][j] = __builtin_amdgcn_mfma_f32_16x16x32_bf16(a[dk][i], b[dk][j],
                                                              acc[i][j], 0, 0, 0);
  }
}

// ---------------------------------------------------------------------------
// Fused QKV projection, 256^2 tiles: Y = x @ [Wq;Wk;Wv]^T + bias.
// grid (9, 128) -> 1152 blocks = 8*144 (bijective XCD swizzle).
// bx 0-2: q, 3-5: k, 6-8: v (256-tile == 1/3 of a 768-wide region, exact).
// Epilogue layouts: q2/k2 [h][tok&255][ (tok>>8)*64+d ], v3 [h][rr*64+d][jc].
// With m0=by*256: rr = by (constant per block), ic/jc = local row.
// ---------------------------------------------------------------------------
__global__ __launch_bounds__(512, 2) void qkv_proj(
    const unsigned short* __restrict__ A, const unsigned short* __restrict__ B,
    const float* __restrict__ bq, const float* __restrict__ bk,
    const float* __restrict__ bv, unsigned short* __restrict__ q2,
    unsigned short* __restrict__ k2, unsigned short* __restrict__ v3, float scaling) {
  __shared__ unsigned short As[16384];
  __shared__ unsigned short Bs[16384];
  const int tid = threadIdx.x, wv = tid >> 6, ln = tid & 63;
  const int wr = wv >> 2, wc = wv & 3;
  const unsigned p = blockIdx.x + blockIdx.y * 9;
  const unsigned l = (p & 7) * 144 + (p >> 3);
  const int bx = l % 9, by = l / 9;
  const int n0 = bx * 256;
  f32x4 acc[8][4] = {};
  gemm256(A + (size_t)by * 256 * 768, 768, B + (size_t)n0 * 768, 768, 768,
          As, Bs, tid, ln, wr * 128, wc * 64, acc);

  const int region = bx / 3;
  const float* bias = region == 0 ? bq : (region == 1 ? bk : bv);
  const float sc = region == 0 ? scaling : 1.0f;
  const int nq0 = n0 - region * 768;
#pragma unroll
  for (int j = 0; j < 4; ++j) {
    const int np = nq0 + wc * 64 + j * 16 + (ln & 15);  // same h for 16-lane grp
    const int h = np >> 6, d = np & 63;
    const float bn = bias[np];
#pragma unroll
    for (int i = 0; i < 8; ++i) {
      const int mloc = wr * 128 + i * 16 + (ln >> 4) * 4;  // local row, 4 consec
      if (region < 2) {
        unsigned short* dst = region == 0 ? q2 : k2;
#pragma unroll
        for (int r = 0; r < 4; ++r)
          dst[(size_t)h * 2097152 + (size_t)(mloc + r) * 8192 + by * 64 + d] =
              f2b((acc[i][j][r] + bn) * sc);
      } else {
        ushort4v o;
#pragma unroll
        for (int r = 0; r < 4; ++r) o[r] = f2b(acc[i][j][r] + bn);
        *(ushort4v*)(v3 + (size_t)h * 2097152 + ((size_t)by * 64 + d) * 256 + mloc) = o;
      }
    }
  }
}

// ---------------------------------------------------------------------------
// QK^T (unchanged R5 structure): per head, K=8192 split 8x. grid (4, 12, 8).
// ---------------------------------------------------------------------------
__global__ __launch_bounds__(256) void qk_gemm(const unsigned short* __restrict__ q2,
                                               const unsigned short* __restrict__ k2,
                                               float* __restrict__ Sp) {
  __shared__ unsigned short As[2 * 128 * 64];
  __shared__ unsigned short Bs[2 * 128 * 64];
  const int tid = threadIdx.x, wv = tid >> 6, ln = tid & 63;
  const int i0 = (blockIdx.x & 1) * 128, j0 = (blockIdx.x >> 1) * 128;
  const int h = blockIdx.y, kc = blockIdx.z;
  const int wm = (wv & 1) * 64, wn = (wv >> 1) * 64;
  f32x4 acc[4][4] = {};
  const unsigned short* Ap = q2 + (size_t)h * 2097152 + (size_t)i0 * 8192 + kc * 1024;
  const unsigned short* Bp = k2 + (size_t)h * 2097152 + (size_t)j0 * 8192 + kc * 1024;
  gemm128(Ap, 8192, Bp, 8192, 1024, As, Bs, wv, ln, wm, wn, acc);
  float* out = Sp + ((size_t)kc * H + h) * 65536;
#pragma unroll
  for (int j = 0; j < 4; ++j) {
    const int jj = j0 + wn + j * 16 + (ln & 15);
#pragma unroll
    for (int i = 0; i < 4; ++i)
#pragma unroll
      for (int r = 0; r < 4; ++r) {
        const int ii = i0 + wm + i * 16 + (ln >> 4) * 4 + r;
        out[(size_t)ii * 256 + jj] = acc[i][j][r];
      }
  }
}

// ---------------------------------------------------------------------------
// Sum 8 K-partials, softmax over j, write fp32 probs (d_out) + bf16 copy (ws).
// ---------------------------------------------------------------------------
__global__ __launch_bounds__(256) void softmax_k(const float* __restrict__ Sp,
                                                 float* __restrict__ P,
                                                 unsigned short* __restrict__ Pb) {
  const int row = blockIdx.x, j = threadIdx.x;  // row = h*C + i
  const size_t stride = (size_t)H * Cc * Cc;    // 786432
  const size_t base = (size_t)row * Cc + j;
  float s = 0.f;
#pragma unroll
  for (int c = 0; c < 8; ++c) s += Sp[base + c * stride];
  float m = s;
#pragma unroll
  for (int o = 32; o > 0; o >>= 1) m = fmaxf(m, __shfl_xor(m, o));
  __shared__ float sm[4], ss[4];
  const int wid = j >> 6, lane = j & 63;
  if (lane == 0) sm[wid] = m;
  __syncthreads();
  m = fmaxf(fmaxf(sm[0], sm[1]), fmaxf(sm[2], sm[3]));
  float e = expf(s - m);
  float t = e;
#pragma unroll
  for (int o = 32; o > 0; o >>= 1) t += __shfl_xor(t, o);
  if (lane == 0) ss[wid] = t;
  __syncthreads();
  t = ss[0] + ss[1] + ss[2] + ss[3];
  const float p = e / t;
  P[base] = p;
  Pb[base] = f2b(p);
}

// ---------------------------------------------------------------------------
// PV, 256^2 tiles: per head C2[i][rd] = sum_j P[h][i][j]*v3[h][rd][j].
// M=256 (one tile), N=8192 -> 32 n-tiles, K=256 (8 steps). grid (32, 12) =
// 384 = 8*48 bijective swizzle; consecutive l share h (P-panel reuse).
// Epilogue scatters straight to token layout for the O-projection.
// ---------------------------------------------------------------------------
__global__ __launch_bounds__(512, 2) void pv_gemm(const unsigned short* __restrict__ P,
                                                  const unsigned short* __restrict__ V,
                                                  unsigned short* __restrict__ Co) {
  __shared__ unsigned short As[16384];
  __shared__ unsigned short Bs[16384];
  const int tid = threadIdx.x, wv = tid >> 6, ln = tid & 63;
  const int wr = wv >> 2, wc = wv & 3;
  const unsigned p = blockIdx.x + blockIdx.y * 32;
  const unsigned l = (p & 7) * 48 + (p >> 3);      // 384 = 8*48
  const int bx = l & 31, h = l >> 5;
  const int n0 = bx * 256;
  f32x4 acc[8][4] = {};
  gemm256(P + (size_t)h * 65536, 256, V + (size_t)h * 2097152 + (size_t)n0 * 256, 256,
          256, As, Bs, tid, ln, wr * 128, wc * 64, acc);
#pragma unroll
  for (int j = 0; j < 4; ++j) {
    const int n = n0 + wc * 64 + j * 16 + (ln & 15);   // rd; rr uniform per grp
    const int rr = n >> 6, d = n & 63;
#pragma unroll
    for (int i = 0; i < 8; ++i)
#pragma unroll
      for (int r = 0; r < 4; ++r) {
        const int ii = wr * 128 + i * 16 + (ln >> 4) * 4 + r;
        Co[((size_t)rr * 256 + ii) * 768 + h * 64 + d] = f2b(acc[i][j][r]);
      }
  }
}

// ---------------------------------------------------------------------------
// Output projection, 256^2 tiles: out = Co @ Wo^T + bo (fp32).
// grid (3, 128) = 384 = 8*48 bijective swizzle.
// ---------------------------------------------------------------------------
__global__ __launch_bounds__(512, 2) void o_proj(const unsigned short* __restrict__ A,
                                                 const unsigned short* __restrict__ B,
                                                 const float* __restrict__ bias,
                                                 float* __restrict__ Y) {
  __shared__ unsigned short As[16384];
  __shared__ unsigned short Bs[16384];
  const int tid = threadIdx.x, wv = tid >> 6, ln = tid & 63;
  const int wr = wv >> 2, wc = wv & 3;
  const unsigned p = blockIdx.x + blockIdx.y * 3;
  const unsigned l = (p & 7) * 48 + (p >> 3);      // 384 = 8*48
  const int bx = l % 3, by = l / 3;
  const int n0 = bx * 256, m0 = by * 256;
  f32x4 acc[8][4] = {};
  gemm256(A + (size_t)m0 * 768, 768, B + (size_t)n0 * 768, 768, 768,
          As, Bs, tid, ln, wr * 128, wc * 64, acc);
#pragma unroll
  for (int j = 0; j < 4; ++j) {
    const int n = n0 + wc * 64 + j * 16 + (ln & 15);
    const float bn = bias[n];
#pragma unroll
    for (int i = 0; i < 8; ++i)
#pragma unroll
      for (int r = 0; r < 4; ++r) {
        const int m = m0 + wr * 128 + i * 16 + (ln >> 4) * 4 + r;
        Y[(size_t)m * 768 + n] = acc[i][j][r] + bn;
      }
  }
}

// ---------------------------------------------------------------------------
extern "C" void kernel_launch(void* const* d_in, const int* in_sizes, int n_in,
                              void* d_out, int out_size, void* d_ws, size_t ws_size,
                              hipStream_t stream) {
  const float* x  = (const float*)d_in[0];
  const float* Wq = (const float*)d_in[1];
  const float* bq = (const float*)d_in[2];
  const float* Wk = (const float*)d_in[3];
  const float* bk = (const float*)d_in[4];
  const float* Wv = (const float*)d_in[5];
  const float* bv = (const float*)d_in[6];
  const float* Wo = (const float*)d_in[7];
  const float* bo = (const float*)d_in[8];
  float* out = (float*)d_out;             // (R,C,1,E)
  float* probs = out + TOK;               // (H,1,C,C)

  char* ws = (char*)d_ws;
  unsigned short* x_bf  = (unsigned short*)(ws);              // 50.3 MB (dead after qkv_proj)
  unsigned short* q2    = (unsigned short*)(ws + 50331648);   // 50.3 MB [h][i][rd]
  unsigned short* k2    = (unsigned short*)(ws + 100663296);  // 50.3 MB [h][j][rd]
  unsigned short* v3    = (unsigned short*)(ws + 150994944);  // 50.3 MB [h][rd][j]
  unsigned short* Wq_bf = (unsigned short*)(ws + 201326592);  // 4 x 1.18 MB contiguous
  unsigned short* Wo_bf = Wq_bf + 3 * 589824;
  // aliases into dead x_bf region:
  float* S_part         = (float*)(ws);                       // 8 x 3.15 MB = 25.2 MB
  unsigned short* P_bf  = (unsigned short*)(ws + 25165824);   // 1.6 MB
  unsigned short* c_bf  = q2;  // q2 dead after qk_gemm

  const float scaling = 0.125f / sqrtf(128.f);  // Dk^-0.5 / sqrt(R)

  cvt_bf16<<<12288, 256, 0, stream>>>(x, x_bf, 3145728);
  cvt_w4<<<1152, 256, 0, stream>>>(Wq, Wk, Wv, Wo, Wq_bf);

  // Fused QKV: N = 2304 (Wq,Wk,Wv contiguous rows), x fetched once.
  qkv_proj<<<dim3(9, 128), 512, 0, stream>>>(x_bf, Wq_bf, bq, bk, bv,
                                             q2, k2, v3, scaling);

  qk_gemm<<<dim3(4, H, 8), 256, 0, stream>>>(q2, k2, S_part);
  softmax_k<<<H * Cc, 256, 0, stream>>>(S_part, probs, P_bf);
  pv_gemm<<<dim3(32, H), 512, 0, stream>>>(P_bf, v3, c_bf);

  o_proj<<<dim3(3, 128), 512, 0, stream>>>(c_bf, Wo_bf, bo, out);
}

// Round 9
// 473.817 us; speedup vs baseline: 1.1153x; 1.1153x over previous
//
#include <hip/hip_runtime.h>
#include <math.h>

typedef short bf16x8 __attribute__((ext_vector_type(8)));
typedef float f32x4 __attribute__((ext_vector_type(4)));
typedef unsigned short ushort8 __attribute__((ext_vector_type(8)));
typedef unsigned short ushort4v __attribute__((ext_vector_type(4)));

constexpr int R = 128, Cc = 256, E = 768, H = 12;
constexpr int M = R * Cc;                 // 32768 tokens
constexpr size_t TOK = (size_t)M * E;     // 25165824

// fp32 -> bf16 round-to-nearest-even
__device__ __forceinline__ unsigned short f2b(float f) {
  unsigned int u = __float_as_uint(f);
  u += 0x7fff + ((u >> 16) & 1);
  return (unsigned short)(u >> 16);
}

// async global->LDS, 16B per lane. LDS dest must be wave-uniform base + lane*16.
__device__ __forceinline__ void ldst16(const unsigned short* g, unsigned short* l) {
  __builtin_amdgcn_global_load_lds(
      (const __attribute__((address_space(1))) unsigned int*)g,
      (__attribute__((address_space(3))) unsigned int*)l, 16, 0, 0);
}

// ---------------------------------------------------------------------------
__global__ __launch_bounds__(256) void cvt_bf16(const float* __restrict__ in,
                                                unsigned short* __restrict__ out,
                                                int n8) {
  int i = blockIdx.x * 256 + threadIdx.x;
  if (i >= n8) return;
  const float4* p = (const float4*)in;
  float4 a = p[2 * i], b = p[2 * i + 1];
  ushort8 o;
  o[0] = f2b(a.x); o[1] = f2b(a.y); o[2] = f2b(a.z); o[3] = f2b(a.w);
  o[4] = f2b(b.x); o[5] = f2b(b.y); o[6] = f2b(b.z); o[7] = f2b(b.w);
  ((ushort8*)out)[i] = o;
}

// All four weight matrices in one launch.
__global__ __launch_bounds__(256) void cvt_w4(const float* __restrict__ W0,
                                              const float* __restrict__ W1,
                                              const float* __restrict__ W2,
                                              const float* __restrict__ W3,
                                              unsigned short* __restrict__ out) {
  const int region = blockIdx.x / 288;
  const int i = (blockIdx.x % 288) * 256 + threadIdx.x;
  if (i >= 73728) return;
  const float* src = region == 0 ? W0 : (region == 1 ? W1 : (region == 2 ? W2 : W3));
  const float4* p = (const float4*)src;
  float4 a = p[2 * i], b = p[2 * i + 1];
  ushort8 o;
  o[0] = f2b(a.x); o[1] = f2b(a.y); o[2] = f2b(a.z); o[3] = f2b(a.w);
  o[4] = f2b(b.x); o[5] = f2b(b.y); o[6] = f2b(b.z); o[7] = f2b(b.w);
  ((ushort8*)(out + (size_t)region * 589824))[i] = o;
}

// ===========================================================================
// 8-PHASE 256x256 GEMM body (m201 template ported to K=768, lda=ldb=768).
// 512 thr = 8 waves (2M x 4N), per-wave 128x64 out (acc[8][4]).
// K-tile = 64; iteration consumes 2 K-tiles (even->buf0, odd->buf1); 12 tiles.
// LDS 128 KB: per parity, A 256x64 (32KB) + B 256x64 (32KB).
// Per phase: [vmcnt at group head] barrier; ds_read quadrant subtile;
//   stage ONE half-tile (2 gload_lds/thread); lgkm(0)+sched_barrier;
//   setprio(1); 16 MFMA; setprio(0).
// Stage slots per 4-phase group consuming tile tc:
//   pg0:(tc+1,B1) pg1:(tc+1,A0) pg2:(tc+1,A1) pg3:(tc+2,B0)
//   Legality: A-halves of a buffer are fully read after that group's pg3
//   (a[0-3] re-read), B-halves after pg2 -> slots above are post-release.
// vmcnt at group head certifies tile tc fully in LDS:
//   outstanding after tc's last half = only the previous pg3 stage = 2 loads
//   -> vmcnt(2); iter0 group0: 8 (prologue T1 in flight); last group: 0.
// Swizzle (both-sides, rule #21): LDS[row][c] = global[row][c ^ (row&7)]
//   realized by pre-swizzled per-lane SOURCE chunk (LDS dest linear);
//   ds_read chunk = (kk*4 + (ln>>4)) ^ (ln&7). 2-way max (free).
// ===========================================================================
__device__ __forceinline__ void stage_half(const unsigned short* __restrict__ G,
                                           int k0, unsigned short* lbase,
                                           int wv, int ln) {
  // one half-tile = 128 rows x 64 k (16 KB); 2 gload_lds per thread.
  const int chunk = ((ln & 7) ^ (ln >> 3)) * 8;   // pre-swizzled source chunk
  const int r0 = wv * 8 + (ln >> 3);
#pragma unroll
  for (int l = 0; l < 2; ++l) {
    const int row = l * 64 + r0;                  // row&7 == ln>>3
    ldst16(G + (size_t)row * 768 + k0 + chunk, lbase + l * 4096 + wv * 512 + ln * 8);
  }
}

__device__ __forceinline__ void gemm256_8ph(
    const unsigned short* __restrict__ At,   // 256 x 768 (row-major, lda 768)
    const unsigned short* __restrict__ Bt,   // 256 x 768
    unsigned short* As, unsigned short* Bs,  // each [2][16384] ushorts
    int wv, int ln, int wm, int wn, f32x4 (&acc)[8][4]) {
  // prologue: T0 {B0,B1,A0,A1}, T1 {B0,B1,A0,A1}
#pragma unroll
  for (int t = 0; t < 2; ++t) {
    stage_half(Bt, t * 64, Bs + t * 16384, wv, ln);                    // B0
    stage_half(Bt + (size_t)128 * 768, t * 64, Bs + t * 16384 + 8192, wv, ln); // B1
    stage_half(At, t * 64, As + t * 16384, wv, ln);                    // A0
    stage_half(At + (size_t)128 * 768, t * 64, As + t * 16384 + 8192, wv, ln); // A1
  }
  const int rw = (ln & 15);                // fragment row within 16-group
  const int rx = ln & 7;                   // swizzle key on read side
  for (int it = 0; it < 6; ++it) {
#pragma unroll
    for (int hi = 0; hi < 2; ++hi) {
      const int tc = 2 * it + hi;          // tile consumed by this group
      const unsigned short* Ab = As + (tc & 1) * 16384;
      const unsigned short* Bb = Bs + (tc & 1) * 16384;
      unsigned short* Asn = As + ((tc + 1) & 1) * 16384;  // buffers for tc+1
      unsigned short* Bsn = Bs + ((tc + 1) & 1) * 16384;
      unsigned short* Bs2 = Bs + (tc & 1) * 16384;        // buffer for tc+2
      const int k1 = (tc + 1) * 64, k2 = (tc + 2) * 64;
      const bool st01 = (hi == 0) ? (it >= 1) : (it <= 4);  // slots pg0-2
      const bool st3 = (it <= 4);                           // slot pg3
      bf16x8 a0[4][2], a1[4][2], b0[2][2], b1[2][2];
      // ---------------- phase 0: Q0 = i0-3 x j0-1 ----------------
      if (hi == 0) {
        if (it == 0) { asm volatile("s_waitcnt vmcnt(8)" ::: "memory"); }
        else         { asm volatile("s_waitcnt vmcnt(2)" ::: "memory"); }
      } else {
        if (it < 5)  { asm volatile("s_waitcnt vmcnt(2)" ::: "memory"); }
        else         { asm volatile("s_waitcnt vmcnt(0)" ::: "memory"); }
      }
      __builtin_amdgcn_sched_barrier(0);
      __builtin_amdgcn_s_barrier();
#pragma unroll
      for (int i = 0; i < 4; ++i)
#pragma unroll
        for (int kk = 0; kk < 2; ++kk)
          a0[i][kk] = *(const bf16x8*)(Ab + (wm + i * 16 + rw) * 64 +
                                       (((kk * 4 + (ln >> 4)) ^ rx) * 8));
#pragma unroll
      for (int j = 0; j < 2; ++j)
#pragma unroll
        for (int kk = 0; kk < 2; ++kk)
          b0[j][kk] = *(const bf16x8*)(Bb + (wn + j * 16 + rw) * 64 +
                                       (((kk * 4 + (ln >> 4)) ^ rx) * 8));
      if (st01) stage_half(Bt + (size_t)128 * 768, k1, Bsn + 8192, wv, ln); // (tc+1,B1)
      asm volatile("s_waitcnt lgkmcnt(0)" ::: "memory");
      __builtin_amdgcn_sched_barrier(0);
      __builtin_amdgcn_s_setprio(1);
#pragma unroll
      for (int i = 0; i < 4; ++i)
#pragma unroll
        for (int j = 0; j < 2; ++j)
#pragma unroll
          for (int kk = 0; kk < 2; ++kk)
            acc[i][j] = __builtin_amdgcn_mfma_f32_16x16x32_bf16(a0[i][kk], b0[j][kk],
                                                                acc[i][j], 0, 0, 0);
      __builtin_amdgcn_s_setprio(0);
      // ---------------- phase 1: Q1 = i4-7 x j0-1 ----------------
      __builtin_amdgcn_s_barrier();
#pragma unroll
      for (int i = 0; i < 4; ++i)
#pragma unroll
        for (int kk = 0; kk < 2; ++kk)
          a1[i][kk] = *(const bf16x8*)(Ab + (wm + (i + 4) * 16 + rw) * 64 +
                                       (((kk * 4 + (ln >> 4)) ^ rx) * 8));
      if (st01) stage_half(At, k1, Asn, wv, ln);                        // (tc+1,A0)
      asm volatile("s_waitcnt lgkmcnt(0)" ::: "memory");
      __builtin_amdgcn_sched_barrier(0);
      __builtin_amdgcn_s_setprio(1);
#pragma unroll
      for (int i = 0; i < 4; ++i)
#pragma unroll
        for (int j = 0; j < 2; ++j)
#pragma unroll
          for (int kk = 0; kk < 2; ++kk)
            acc[i + 4][j] = __builtin_amdgcn_mfma_f32_16x16x32_bf16(a1[i][kk], b0[j][kk],
                                                                    acc[i + 4][j], 0, 0, 0);
      __builtin_amdgcn_s_setprio(0);
      // ---------------- phase 2: Q2 = i4-7 x j2-3 ----------------
      __builtin_amdgcn_s_barrier();
#pragma unroll
      for (int j = 0; j < 2; ++j)
#pragma unroll
        for (int kk = 0; kk < 2; ++kk)
          b1[j][kk] = *(const bf16x8*)(Bb + (wn + (j + 2) * 16 + rw) * 64 +
                                       (((kk * 4 + (ln >> 4)) ^ rx) * 8));
      if (st01) stage_half(At + (size_t)128 * 768, k1, Asn + 8192, wv, ln); // (tc+1,A1)
      asm volatile("s_waitcnt lgkmcnt(0)" ::: "memory");
      __builtin_amdgcn_sched_barrier(0);
      __builtin_amdgcn_s_setprio(1);
#pragma unroll
      for (int i = 0; i < 4; ++i)
#pragma unroll
        for (int j = 0; j < 2; ++j)
#pragma unroll
          for (int kk = 0; kk < 2; ++kk)
            acc[i + 4][j + 2] = __builtin_amdgcn_mfma_f32_16x16x32_bf16(
                a1[i][kk], b1[j][kk], acc[i + 4][j + 2], 0, 0, 0);
      __builtin_amdgcn_s_setprio(0);
      // ---------------- phase 3: Q3 = i0-3 x j2-3 ----------------
      __builtin_amdgcn_s_barrier();
#pragma unroll
      for (int i = 0; i < 4; ++i)
#pragma unroll
        for (int kk = 0; kk < 2; ++kk)
          a0[i][kk] = *(const bf16x8*)(Ab + (wm + i * 16 + rw) * 64 +
                                       (((kk * 4 + (ln >> 4)) ^ rx) * 8));
      if (st3) stage_half(Bt, k2, Bs2, wv, ln);                         // (tc+2,B0)
      asm volatile("s_waitcnt lgkmcnt(0)" ::: "memory");
      __builtin_amdgcn_sched_barrier(0);
      __builtin_amdgcn_s_setprio(1);
#pragma unroll
      for (int i = 0; i < 4; ++i)
#pragma unroll
        for (int j = 0; j < 2; ++j)
#pragma unroll
          for (int kk = 0; kk < 2; ++kk)
            acc[i][j + 2] = __builtin_amdgcn_mfma_f32_16x16x32_bf16(
                a0[i][kk], b1[j][kk], acc[i][j + 2], 0, 0, 0);
      __builtin_amdgcn_s_setprio(0);
    }
  }
}

// ===========================================================================
// 128x128-tile body (R5 verbatim — proven at 492 total) for qk/pv/o_proj.
// ===========================================================================
__device__ __forceinline__ void stage64(const unsigned short* __restrict__ A, int lda,
                                        const unsigned short* __restrict__ B, int ldb,
                                        int k0, unsigned short* As, unsigned short* Bs,
                                        int wv, int ln, int srow, int scol) {
#pragma unroll
  for (int t = 0; t < 4; ++t) {
    const int ch = wv * 4 + t;
    const int row = ch * 8 + srow;
    ldst16(A + (size_t)row * lda + k0 + scol, As + ch * 512 + ln * 8);
    ldst16(B + (size_t)row * ldb + k0 + scol, Bs + ch * 512 + ln * 8);
  }
}

__device__ __forceinline__ void gemm128(const unsigned short* __restrict__ A, int lda,
                                        const unsigned short* __restrict__ B, int ldb,
                                        int K, unsigned short* As, unsigned short* Bs,
                                        int wv, int ln, int wm, int wn,
                                        f32x4 (&acc)[4][4]) {
  const int srow = ln >> 3;
  const int scol = ((ln & 7) ^ srow) * 8;
  const int nt = K >> 6;
  stage64(A, lda, B, ldb, 0, As, Bs, wv, ln, srow, scol);
  if (nt > 1)
    stage64(A, lda, B, ldb, 64, As + 8192, Bs + 8192, wv, ln, srow, scol);
  for (int t = 0; t < nt; ++t) {
    const int cur = t & 1;
    if (t + 1 < nt) {
      asm volatile("s_waitcnt vmcnt(8)" ::: "memory");
    } else {
      asm volatile("s_waitcnt vmcnt(0)" ::: "memory");
    }
    __builtin_amdgcn_sched_barrier(0);
    __builtin_amdgcn_s_barrier();
    const unsigned short* Ab = As + cur * 8192;
    const unsigned short* Bb = Bs + cur * 8192;
    bf16x8 a[2][4], b[2][4];
#pragma unroll
    for (int dk = 0; dk < 2; ++dk) {
      const int rc = ((dk * 4 + (ln >> 4)) ^ (ln & 7)) * 8;
#pragma unroll
      for (int i = 0; i < 4; ++i)
        a[dk][i] = *(const bf16x8*)(Ab + (wm + i * 16 + (ln & 15)) * 64 + rc);
#pragma unroll
      for (int j = 0; j < 4; ++j)
        b[dk][j] = *(const bf16x8*)(Bb + (wn + j * 16 + (ln & 15)) * 64 + rc);
    }
    asm volatile("s_waitcnt lgkmcnt(0)" ::: "memory");
    __builtin_amdgcn_sched_barrier(0);
    __builtin_amdgcn_s_barrier();
    if (t + 2 < nt)
      stage64(A, lda, B, ldb, (t + 2) * 64, As + cur * 8192, Bs + cur * 8192,
              wv, ln, srow, scol);
#pragma unroll
    for (int dk = 0; dk < 2; ++dk)
#pragma unroll
      for (int i = 0; i < 4; ++i)
#pragma unroll
        for (int j = 0; j < 4; ++j)
          acc[i][j] = __builtin_amdgcn_mfma_f32_16x16x32_bf16(a[dk][i], b[dk][j],
                                                              acc[i][j], 0, 0, 0);
  }
}

// ---------------------------------------------------------------------------
// Fused QKV projection, 8-phase 256^2 tiles.
// grid (9, 128) -> 1152 = 8*144 bijective XCD swizzle.
// bx 0-2: q, 3-5: k, 6-8: v. Epilogue layouts (verified R8):
//   q2/k2 [h][ic][rr*64+d], v3 [h][rr*64+d][jc], rr = by.
// ---------------------------------------------------------------------------
__global__ __launch_bounds__(512, 1) void qkv_proj(
    const unsigned short* __restrict__ A, const unsigned short* __restrict__ B,
    const float* __restrict__ bq, const float* __restrict__ bk,
    const float* __restrict__ bv, unsigned short* __restrict__ q2,
    unsigned short* __restrict__ k2, unsigned short* __restrict__ v3, float scaling) {
  __shared__ unsigned short As[2 * 16384];
  __shared__ unsigned short Bs[2 * 16384];
  const int tid = threadIdx.x, wv = tid >> 6, ln = tid & 63;
  const int wr = wv >> 2, wc = wv & 3;
  const unsigned p = blockIdx.x + blockIdx.y * 9;
  const unsigned l = (p & 7) * 144 + (p >> 3);
  const int bx = l % 9, by = l / 9;
  const int n0 = bx * 256;
  f32x4 acc[8][4] = {};
  gemm256_8ph(A + (size_t)by * 256 * 768, B + (size_t)n0 * 768,
              As, Bs, wv, ln, wr * 128, wc * 64, acc);

  const int region = bx / 3;
  const float* bias = region == 0 ? bq : (region == 1 ? bk : bv);
  const float sc = region == 0 ? scaling : 1.0f;
  const int nq0 = n0 - region * 768;
#pragma unroll
  for (int j = 0; j < 4; ++j) {
    const int np = nq0 + wc * 64 + j * 16 + (ln & 15);  // same h for 16-lane grp
    const int h = np >> 6, d = np & 63;
    const float bn = bias[np];
#pragma unroll
    for (int i = 0; i < 8; ++i) {
      const int mloc = wr * 128 + i * 16 + (ln >> 4) * 4;  // local row, 4 consec
      if (region < 2) {
        unsigned short* dst = region == 0 ? q2 : k2;
#pragma unroll
        for (int r = 0; r < 4; ++r)
          dst[(size_t)h * 2097152 + (size_t)(mloc + r) * 8192 + by * 64 + d] =
              f2b((acc[i][j][r] + bn) * sc);
      } else {
        ushort4v o;
#pragma unroll
        for (int r = 0; r < 4; ++r) o[r] = f2b(acc[i][j][r] + bn);
        *(ushort4v*)(v3 + (size_t)h * 2097152 + ((size_t)by * 64 + d) * 256 + mloc) = o;
      }
    }
  }
}

// ---------------------------------------------------------------------------
// QK^T (R5): per head, K=8192 split 8x. grid (4, 12, 8).
// ---------------------------------------------------------------------------
__global__ __launch_bounds__(256) void qk_gemm(const unsigned short* __restrict__ q2,
                                               const unsigned short* __restrict__ k2,
                                               float* __restrict__ Sp) {
  __shared__ unsigned short As[2 * 128 * 64];
  __shared__ unsigned short Bs[2 * 128 * 64];
  const int tid = threadIdx.x, wv = tid >> 6, ln = tid & 63;
  const int i0 = (blockIdx.x & 1) * 128, j0 = (blockIdx.x >> 1) * 128;
  const int h = blockIdx.y, kc = blockIdx.z;
  const int wm = (wv & 1) * 64, wn = (wv >> 1) * 64;
  f32x4 acc[4][4] = {};
  const unsigned short* Ap = q2 + (size_t)h * 2097152 + (size_t)i0 * 8192 + kc * 1024;
  const unsigned short* Bp = k2 + (size_t)h * 2097152 + (size_t)j0 * 8192 + kc * 1024;
  gemm128(Ap, 8192, Bp, 8192, 1024, As, Bs, wv, ln, wm, wn, acc);
  float* out = Sp + ((size_t)kc * H + h) * 65536;
#pragma unroll
  for (int j = 0; j < 4; ++j) {
    const int jj = j0 + wn + j * 16 + (ln & 15);
#pragma unroll
    for (int i = 0; i < 4; ++i)
#pragma unroll
      for (int r = 0; r < 4; ++r) {
        const int ii = i0 + wm + i * 16 + (ln >> 4) * 4 + r;
        out[(size_t)ii * 256 + jj] = acc[i][j][r];
      }
  }
}

// ---------------------------------------------------------------------------
// Sum 8 K-partials, softmax over j, write fp32 probs (d_out) + bf16 copy (ws).
// ---------------------------------------------------------------------------
__global__ __launch_bounds__(256) void softmax_k(const float* __restrict__ Sp,
                                                 float* __restrict__ P,
                                                 unsigned short* __restrict__ Pb) {
  const int row = blockIdx.x, j = threadIdx.x;  // row = h*C + i
  const size_t stride = (size_t)H * Cc * Cc;    // 786432
  const size_t base = (size_t)row * Cc + j;
  float s = 0.f;
#pragma unroll
  for (int c = 0; c < 8; ++c) s += Sp[base + c * stride];
  float m = s;
#pragma unroll
  for (int o = 32; o > 0; o >>= 1) m = fmaxf(m, __shfl_xor(m, o));
  __shared__ float sm[4], ss[4];
  const int wid = j >> 6, lane = j & 63;
  if (lane == 0) sm[wid] = m;
  __syncthreads();
  m = fmaxf(fmaxf(sm[0], sm[1]), fmaxf(sm[2], sm[3]));
  float e = expf(s - m);
  float t = e;
#pragma unroll
  for (int o = 32; o > 0; o >>= 1) t += __shfl_xor(t, o);
  if (lane == 0) ss[wid] = t;
  __syncthreads();
  t = ss[0] + ss[1] + ss[2] + ss[3];
  const float p = e / t;
  P[base] = p;
  Pb[base] = f2b(p);
}

// ---------------------------------------------------------------------------
// PV (R5): per head C2[i][rd] = sum_j P[h][i][j]*v3[h][rd][j]. grid (128,12).
// ---------------------------------------------------------------------------
__global__ __launch_bounds__(256) void pv_gemm(const unsigned short* __restrict__ P,
                                               const unsigned short* __restrict__ V,
                                               unsigned short* __restrict__ Co) {
  __shared__ unsigned short As[2 * 128 * 64];
  __shared__ unsigned short Bs[2 * 128 * 64];
  const int tid = threadIdx.x, wv = tid >> 6, ln = tid & 63;
  const unsigned p = blockIdx.x + blockIdx.y * 128;
  const unsigned l = (p & 7) * 192 + (p >> 3);     // nwg = 1536 = 8*192
  const int bx = l & 127, h = l >> 7;
  const int i0 = (bx & 1) * 128, n0 = (bx >> 1) * 128;
  const int wm = (wv & 1) * 64, wn = (wv >> 1) * 64;
  f32x4 acc[4][4] = {};
  const unsigned short* Ap = P + (size_t)h * 65536 + (size_t)i0 * 256;
  const unsigned short* Bp = V + (size_t)h * 2097152 + (size_t)n0 * 256;
  gemm128(Ap, 256, Bp, 256, 256, As, Bs, wv, ln, wm, wn, acc);
#pragma unroll
  for (int j = 0; j < 4; ++j) {
    const int n = n0 + wn + j * 16 + (ln & 15);    // rd; same rr for 16-lane grp
    const int rr = n >> 6, d = n & 63;
#pragma unroll
    for (int i = 0; i < 4; ++i)
#pragma unroll
      for (int r = 0; r < 4; ++r) {
        const int ii = i0 + wm + i * 16 + (ln >> 4) * 4 + r;
        Co[((size_t)rr * 256 + ii) * 768 + h * 64 + d] = f2b(acc[i][j][r]);
      }
  }
}

// ---------------------------------------------------------------------------
// Output projection (R5): out = Co @ Wo^T + bo (fp32), XCD-swizzled.
// ---------------------------------------------------------------------------
__global__ __launch_bounds__(256) void o_proj(const unsigned short* __restrict__ A,
                                              const unsigned short* __restrict__ B,
                                              const float* __restrict__ bias,
                                              float* __restrict__ Y) {
  __shared__ unsigned short As[2 * 128 * 64];
  __shared__ unsigned short Bs[2 * 128 * 64];
  const int tid = threadIdx.x, wv = tid >> 6, ln = tid & 63;
  const unsigned p = blockIdx.x + blockIdx.y * 6;
  const unsigned l = (p & 7) * 192 + (p >> 3);     // nwg = 1536 = 8*192
  const int bx = l % 6, by = l / 6;
  const int n0 = bx * 128, m0 = by * 128;
  const int wm = (wv & 1) * 64, wn = (wv >> 1) * 64;
  f32x4 acc[4][4] = {};
  gemm128(A + (size_t)m0 * 768, 768, B + (size_t)n0 * 768, 768, 768,
          As, Bs, wv, ln, wm, wn, acc);
#pragma unroll
  for (int j = 0; j < 4; ++j) {
    const int n = n0 + wn + j * 16 + (ln & 15);
    const float bn = bias[n];
#pragma unroll
    for (int i = 0; i < 4; ++i)
#pragma unroll
      for (int r = 0; r < 4; ++r) {
        const int m = m0 + wm + i * 16 + (ln >> 4) * 4 + r;
        Y[(size_t)m * 768 + n] = acc[i][j][r] + bn;
      }
  }
}

// ---------------------------------------------------------------------------
extern "C" void kernel_launch(void* const* d_in, const int* in_sizes, int n_in,
                              void* d_out, int out_size, void* d_ws, size_t ws_size,
                              hipStream_t stream) {
  const float* x  = (const float*)d_in[0];
  const float* Wq = (const float*)d_in[1];
  const float* bq = (const float*)d_in[2];
  const float* Wk = (const float*)d_in[3];
  const float* bk = (const float*)d_in[4];
  const float* Wv = (const float*)d_in[5];
  const float* bv = (const float*)d_in[6];
  const float* Wo = (const float*)d_in[7];
  const float* bo = (const float*)d_in[8];
  float* out = (float*)d_out;             // (R,C,1,E)
  float* probs = out + TOK;               // (H,1,C,C)

  char* ws = (char*)d_ws;
  unsigned short* x_bf  = (unsigned short*)(ws);              // 50.3 MB (dead after qkv_proj)
  unsigned short* q2    = (unsigned short*)(ws + 50331648);   // 50.3 MB [h][i][rd]
  unsigned short* k2    = (unsigned short*)(ws + 100663296);  // 50.3 MB [h][j][rd]
  unsigned short* v3    = (unsigned short*)(ws + 150994944);  // 50.3 MB [h][rd][j]
  unsigned short* Wq_bf = (unsigned short*)(ws + 201326592);  // 4 x 1.18 MB contiguous
  unsigned short* Wo_bf = Wq_bf + 3 * 589824;
  // aliases into dead x_bf region:
  float* S_part         = (float*)(ws);                       // 8 x 3.15 MB = 25.2 MB
  unsigned short* P_bf  = (unsigned short*)(ws + 25165824);   // 1.6 MB
  unsigned short* c_bf  = q2;  // q2 dead after qk_gemm

  const float scaling = 0.125f / sqrtf(128.f);  // Dk^-0.5 / sqrt(R)

  cvt_bf16<<<12288, 256, 0, stream>>>(x, x_bf, 3145728);
  cvt_w4<<<1152, 256, 0, stream>>>(Wq, Wk, Wv, Wo, Wq_bf);

  // Fused QKV: N = 2304 (Wq,Wk,Wv contiguous rows), x fetched once.
  qkv_proj<<<dim3(9, 128), 512, 0, stream>>>(x_bf, Wq_bf, bq, bk, bv,
                                             q2, k2, v3, scaling);

  qk_gemm<<<dim3(4, H, 8), 256, 0, stream>>>(q2, k2, S_part);
  softmax_k<<<H * Cc, 256, 0, stream>>>(S_part, probs, P_bf);
  pv_gemm<<<dim3(128, H), 256, 0, stream>>>(P_bf, v3, c_bf);

  o_proj<<<dim3(6, 256), 256, 0, stream>>>(c_bf, Wo_bf, bo, out);
}